// Round 2
// baseline (124.307 us; speedup 1.0000x reference)
//
#include <hip/hip_runtime.h>

// Problem constants (from reference): x (B,I); w/s/t (O,I); out (B,O), all fp32.
#define B_SZ 256
#define O_SZ 1024
#define I_SZ 1024

#define TB  8                 // b-values accumulated per wave (per lane, in regs)
#define OG  4                 // o-rows per wave
#define LPG 16                // lanes per o-group (64 / OG)
#define KITERS (I_SZ / (LPG * 4))   // 16: each lane covers 4 floats per k

// out[b,o] = sum_i w[o,i] * phi((x[b,i]-t[o,i])/s[o,i]),  phi(z) = -z*exp(-0.5 z^2)
// exp(-0.5 z^2) = exp2(z^2 * (-0.5*log2(e)))
__launch_bounds__(256)
__global__ void wavkan_dog_kernel(const float* __restrict__ X,
                                  const float* __restrict__ W,
                                  const float* __restrict__ S,
                                  const float* __restrict__ T,
                                  float* __restrict__ Out) {
    const int tid  = threadIdx.x;
    const int wave = tid >> 6;        // 0..3
    const int lane = tid & 63;
    const int grp  = lane >> 4;       // 0..3  (o-group within wave)
    const int sl   = lane & (LPG - 1);// 0..15 (lane within o-group, splits i)

    const int o  = blockIdx.x * (4 * OG) + wave * OG + grp;  // 16 o's per block
    const int b0 = blockIdx.y * TB;

    const float C = -0.72134752044448170368f; // -0.5 * log2(e)

    float acc[TB];
#pragma unroll
    for (int j = 0; j < TB; ++j) acc[j] = 0.0f;

    const size_t row = (size_t)o * I_SZ + (size_t)(sl * 4);
    const float* wrow = W + row;
    const float* srow = S + row;
    const float* trow = T + row;
    const float* xcol = X + (size_t)b0 * I_SZ + (size_t)(sl * 4);

#pragma unroll 2
    for (int k = 0; k < KITERS; ++k) {
        const int i = k * (LPG * 4);

        const float4 w4 = *(const float4*)(wrow + i);
        const float4 s4 = *(const float4*)(srow + i);
        const float4 t4 = *(const float4*)(trow + i);

        float4 xv[TB];
#pragma unroll
        for (int j = 0; j < TB; ++j)
            xv[j] = *(const float4*)(xcol + (size_t)j * I_SZ + i);

        float wa[4] = {w4.x, w4.y, w4.z, w4.w};
        float sa[4] = {s4.x, s4.y, s4.z, s4.w};
        float ta[4] = {t4.x, t4.y, t4.z, t4.w};
        float xa[TB][4];
#pragma unroll
        for (int j = 0; j < TB; ++j) {
            xa[j][0] = xv[j].x; xa[j][1] = xv[j].y;
            xa[j][2] = xv[j].z; xa[j][3] = xv[j].w;
        }

#pragma unroll
        for (int c = 0; c < 4; ++c) {
            const float rs  = __builtin_amdgcn_rcpf(sa[c]); // v_rcp_f32, amortized over TB
            const float trs = ta[c] * rs;
            const float wv  = wa[c];
#pragma unroll
            for (int j = 0; j < TB; ++j) {
                const float z = fmaf(xa[j][c], rs, -trs);          // (x - t)/s
                const float e = __builtin_amdgcn_exp2f(z * z * C); // exp(-0.5 z^2)
                acc[j] = fmaf(-wv, z * e, acc[j]);                 // += w * (-z*e)
            }
        }
    }

    // Reduce acc[] across the 16 lanes of this o-group (xor masks 1,2,4,8 stay in-group).
#pragma unroll
    for (int m = 1; m < LPG; m <<= 1) {
#pragma unroll
        for (int j = 0; j < TB; ++j)
            acc[j] += __shfl_xor(acc[j], m, 64);
    }

    // Lanes 0..TB-1 of each group write out[b0+sl, o].
    if (sl < TB) {
        float v = 0.0f;
#pragma unroll
        for (int j = 0; j < TB; ++j)
            if (sl == j) v = acc[j];   // static unrolled select (no scratch)
        Out[(size_t)(b0 + sl) * O_SZ + o] = v;
    }
}

extern "C" void kernel_launch(void* const* d_in, const int* in_sizes, int n_in,
                              void* d_out, int out_size, void* d_ws, size_t ws_size,
                              hipStream_t stream) {
    const float* x = (const float*)d_in[0];   // (B, I)
    const float* w = (const float*)d_in[1];   // (O, I)
    const float* s = (const float*)d_in[2];   // (O, I)
    const float* t = (const float*)d_in[3];   // (O, I)
    float* out = (float*)d_out;               // (B, O)

    dim3 grid(O_SZ / (4 * OG), B_SZ / TB);    // (64, 32) = 2048 blocks
    wavkan_dog_kernel<<<grid, 256, 0, stream>>>(x, w, s, t, out);
}

// Round 3
// 118.450 us; speedup vs baseline: 1.0494x; 1.0494x over previous
//
#include <hip/hip_runtime.h>

// x (B,I); w/s/t (O,I); out (B,O), all fp32.
#define B_SZ 256
#define O_SZ 1024
#define I_SZ 1024

#define TB  8      // b-values per lane (accumulated in regs)
#define MO  2      // o-values per lane (x-load reuse)
#define SLN 32     // lanes splitting i (per half-wave)
#define KITERS (I_SZ / (SLN * 4))   // 8: 128 floats of i per iter

// out[b,o] = sum_i w[o,i] * phi((x[b,i]-t[o,i])/s[o,i]),  phi(z) = -z*exp(-0.5 z^2)
// exp(-0.5 z^2) = exp2(z^2 * (-0.5*log2(e)))
__launch_bounds__(256, 4)
__global__ void wavkan_dog_kernel(const float* __restrict__ X,
                                  const float* __restrict__ W,
                                  const float* __restrict__ S,
                                  const float* __restrict__ T,
                                  float* __restrict__ Out) {
    const int tid  = threadIdx.x;
    const int wave = tid >> 6;        // 0..3
    const int lane = tid & 63;
    const int half = lane >> 5;       // 0..1 : which o-pair within the wave
    const int sl   = lane & (SLN - 1);// 0..31: i-split lane

    // 16 o's per block: wave*4 + half*2 + {0,1}
    const int o0 = blockIdx.x * 16 + wave * 4 + half * MO;
    const int b0 = blockIdx.y * TB;

    const float C = -0.72134752044448170368f; // -0.5 * log2(e)

    float acc[MO][TB];
#pragma unroll
    for (int oo = 0; oo < MO; ++oo)
#pragma unroll
        for (int j = 0; j < TB; ++j) acc[oo][j] = 0.0f;

    const size_t r0 = (size_t)o0 * I_SZ + (size_t)(sl * 4);
    const float* w0 = W + r0;           const float* w1 = w0 + I_SZ;
    const float* s0 = S + r0;           const float* s1 = s0 + I_SZ;
    const float* t0 = T + r0;           const float* t1 = t0 + I_SZ;
    const float* xc = X + (size_t)b0 * I_SZ + (size_t)(sl * 4);

    for (int k = 0; k < KITERS; ++k) {
        const int i = k * (SLN * 4);

        // 14 VMEM, batched up front
        const float4 w4[MO] = { *(const float4*)(w0 + i), *(const float4*)(w1 + i) };
        const float4 s4[MO] = { *(const float4*)(s0 + i), *(const float4*)(s1 + i) };
        const float4 t4[MO] = { *(const float4*)(t0 + i), *(const float4*)(t1 + i) };
        float4 xv[TB];
#pragma unroll
        for (int j = 0; j < TB; ++j)
            xv[j] = *(const float4*)(xc + (size_t)j * I_SZ + i);

        // derived per-(o,c) params; frees raw w/s/t regs
        float rs[MO][4], trs[MO][4], wv[MO][4];
#pragma unroll
        for (int oo = 0; oo < MO; ++oo) {
            const float sa[4] = {s4[oo].x, s4[oo].y, s4[oo].z, s4[oo].w};
            const float ta[4] = {t4[oo].x, t4[oo].y, t4[oo].z, t4[oo].w};
            const float wa[4] = {w4[oo].x, w4[oo].y, w4[oo].z, w4[oo].w};
#pragma unroll
            for (int c = 0; c < 4; ++c) {
                rs[oo][c]  = __builtin_amdgcn_rcpf(sa[c]);
                trs[oo][c] = ta[c] * rs[oo][c];
                wv[oo][c]  = wa[c];
            }
        }

#pragma unroll
        for (int c = 0; c < 4; ++c) {
            const float xs[TB] = { ((const float*)&xv[0])[c], ((const float*)&xv[1])[c],
                                   ((const float*)&xv[2])[c], ((const float*)&xv[3])[c],
                                   ((const float*)&xv[4])[c], ((const float*)&xv[5])[c],
                                   ((const float*)&xv[6])[c], ((const float*)&xv[7])[c] };
#pragma unroll
            for (int oo = 0; oo < MO; ++oo) {
                const float r = rs[oo][c], tr = trs[oo][c], wq = wv[oo][c];
#pragma unroll
                for (int j = 0; j < TB; ++j) {
                    const float z = fmaf(xs[j], r, -tr);               // (x-t)/s
                    const float e = __builtin_amdgcn_exp2f(z * z * C); // exp(-z^2/2)
                    acc[oo][j] = fmaf(-wq, z * e, acc[oo][j]);         // += w*(-z*e)
                }
            }
        }
    }

    // Reduce across the 32 i-split lanes (xor 1,2,4,8,16 stay within the half)
#pragma unroll
    for (int m = 1; m < SLN; m <<= 1)
#pragma unroll
        for (int oo = 0; oo < MO; ++oo)
#pragma unroll
            for (int j = 0; j < TB; ++j)
                acc[oo][j] += __shfl_xor(acc[oo][j], m, 64);

    // Lanes sl<TB write out[b0+sl, o0..o0+1] (contiguous pair -> float2)
    if (sl < TB) {
        float v0 = 0.0f, v1 = 0.0f;
#pragma unroll
        for (int j = 0; j < TB; ++j)
            if (sl == j) { v0 = acc[0][j]; v1 = acc[1][j]; }
        *(float2*)(Out + (size_t)(b0 + sl) * O_SZ + o0) = make_float2(v0, v1);
    }
}

extern "C" void kernel_launch(void* const* d_in, const int* in_sizes, int n_in,
                              void* d_out, int out_size, void* d_ws, size_t ws_size,
                              hipStream_t stream) {
    const float* x = (const float*)d_in[0];   // (B, I)
    const float* w = (const float*)d_in[1];   // (O, I)
    const float* s = (const float*)d_in[2];   // (O, I)
    const float* t = (const float*)d_in[3];   // (O, I)
    float* out = (float*)d_out;               // (B, O)

    dim3 grid(O_SZ / 16, B_SZ / TB);          // (64, 32) = 2048 blocks
    wavkan_dog_kernel<<<grid, 256, 0, stream>>>(x, w, s, t, out);
}